// Round 5
// baseline (1671.469 us; speedup 1.0000x reference)
//
#include <hip/hip_runtime.h>
#include <cstdint>
#include <cstddef>

#define B_    16
#define N_    4096
#define S_    1024
#define K_    32
#define COUT_ 128
#define NQ_   (B_*S_)

// ---------------- Kernel 1: FPS, 2 clouds per block ----------------
// 8 blocks x 256 threads; ~105 KB static LDS -> 1 block/CU. The two clouds'
// scan/DPP/select chains are independent -> ILP hides each other's latency,
// and one barrier serves two FPS steps (R4 post-mortem: per-step overhead
// ~1000cyc was the target, not the 384cyc throughput-bound scan).
#define FT 256
#define FP (N_/FT)    // 16 points per thread per cloud

// wave64 max-reduce of u64 key via DPP; lane 63 holds the result.
__device__ __forceinline__ uint64_t wave_max_u64_l63(uint64_t key) {
  uint32_t lo = (uint32_t)key, hi = (uint32_t)(key >> 32);
#define DPP_STEP(ctrl) { \
    uint32_t lo2 = (uint32_t)__builtin_amdgcn_update_dpp((int)lo, (int)lo, (ctrl), 0xf, 0xf, false); \
    uint32_t hi2 = (uint32_t)__builtin_amdgcn_update_dpp((int)hi, (int)hi, (ctrl), 0xf, 0xf, false); \
    const bool gt = (hi2 > hi) || (hi2 == hi && lo2 > lo); \
    hi = gt ? hi2 : hi; lo = gt ? lo2 : lo; \
  }
  DPP_STEP(0x111)  // row_shr:1
  DPP_STEP(0x112)  // row_shr:2
  DPP_STEP(0x114)  // row_shr:4
  DPP_STEP(0x118)  // row_shr:8
  DPP_STEP(0x142)  // row_bcast:15
  DPP_STEP(0x143)  // row_bcast:31
#undef DPP_STEP
  return ((uint64_t)hi << 32) | lo;
}

__global__ __launch_bounds__(FT) void fps2_kernel(
    const float* __restrict__ pos, float* __restrict__ qpos_out,
    float* __restrict__ batch_out)
{
  __shared__ float px[2][N_], py[2][N_], pz[2][N_];   // 96 KiB
  __shared__ int   hist[2][S_];                       // 8 KiB
  __shared__ unsigned long long wkey[2][2][4];        // [cloud][parity][wave]
  __shared__ float wx[2][2][4], wy[2][2][4], wz[2][2][4];

  const int t = threadIdx.x;
  const int lane = t & 63, wid = t >> 6;
  const int bA = blockIdx.x * 2, bB = bA + 1;
  const float* pA = pos + (size_t)bA * N_ * 3;
  const float* pB = pos + (size_t)bB * N_ * 3;

  for (int i = t; i < N_; i += FT) {
    px[0][i] = pA[i*3+0]; py[0][i] = pA[i*3+1]; pz[0][i] = pA[i*3+2];
    px[1][i] = pB[i*3+0]; py[1][i] = pB[i*3+1]; pz[1][i] = pB[i*3+2];
  }
  for (int s = t; s < S_; s += FT) {
    batch_out[(size_t)bA*S_ + s] = (float)bA;
    batch_out[(size_t)bB*S_ + s] = (float)bB;
  }
  __syncthreads();

  float rxA[FP], ryA[FP], rzA[FP], mindA[FP];
  float rxB[FP], ryB[FP], rzB[FP], mindB[FP];
  #pragma unroll
  for (int k = 0; k < FP; ++k) {
    const int p = k*FT + t;
    rxA[k] = px[0][p]; ryA[k] = py[0][p]; rzA[k] = pz[0][p]; mindA[k] = INFINITY;
    rxB[k] = px[1][p]; ryB[k] = py[1][p]; rzB[k] = pz[1][p]; mindB[k] = INFINITY;
  }

  int lastA = 0, lastB = 0;
  float lxA = px[0][0], lyA = py[0][0], lzA = pz[0][0];
  float lxB = px[1][0], lyB = py[1][0], lzB = pz[1][0];

  for (int s = 0; s < S_; ++s) {
    if (t == 0) { hist[0][s] = lastA; hist[1][s] = lastB; }
    if (s == S_-1) break;

    // ---- scan A ----
    float bmA = -1.0f; int kbA = 0;
    #pragma unroll
    for (int k = 0; k < FP; ++k) {
      #pragma clang fp contract(off)
      const float dx = rxA[k]-lxA;
      const float dy = ryA[k]-lyA;
      const float dz = rzA[k]-lzA;
      const float d  = dx*dx + dy*dy + dz*dz;   // exact ref order, no FMA
      const float m  = fminf(mindA[k], d);
      mindA[k] = m;
      if (m > bmA) { bmA = m; kbA = k; }        // strict > keeps lowest k
    }
    // ---- scan B ----
    float bmB = -1.0f; int kbB = 0;
    #pragma unroll
    for (int k = 0; k < FP; ++k) {
      #pragma clang fp contract(off)
      const float dx = rxB[k]-lxB;
      const float dy = ryB[k]-lyB;
      const float dz = rzB[k]-lzB;
      const float d  = dx*dx + dy*dy + dz*dz;
      const float m  = fminf(mindB[k], d);
      mindB[k] = m;
      if (m > bmB) { bmB = m; kbB = k; }
    }
    // max key == (max dist, then min point index): lo = 4095 - p
    uint64_t keyA = ((uint64_t)__float_as_uint(bmA) << 32)
                  | (uint32_t)((N_-1) - (kbA*FT + t));
    uint64_t keyB = ((uint64_t)__float_as_uint(bmB) << 32)
                  | (uint32_t)((N_-1) - (kbB*FT + t));
    keyA = wave_max_u64_l63(keyA);              // two independent DPP chains
    keyB = wave_max_u64_l63(keyB);              // -> interleaved issue
    const int par = s & 1;
    if (lane == 63) {
      const int pa = (N_-1) - (int)(uint32_t)keyA;
      const int pb = (N_-1) - (int)(uint32_t)keyB;
      wkey[0][par][wid] = keyA;                 // prefetch winner coords pre-barrier
      wx[0][par][wid] = px[0][pa]; wy[0][par][wid] = py[0][pa]; wz[0][par][wid] = pz[0][pa];
      wkey[1][par][wid] = keyB;
      wx[1][par][wid] = px[1][pb]; wy[1][par][wid] = py[1][pb]; wz[1][par][wid] = pz[1][pb];
    }
    __syncthreads();                            // ONE barrier for both clouds
    {
      uint64_t k0 = wkey[0][par][0], k1 = wkey[0][par][1];
      uint64_t k2 = wkey[0][par][2], k3 = wkey[0][par][3];
      float x0=wx[0][par][0], x1=wx[0][par][1], x2=wx[0][par][2], x3=wx[0][par][3];
      float y0=wy[0][par][0], y1=wy[0][par][1], y2=wy[0][par][2], y3=wy[0][par][3];
      float z0=wz[0][par][0], z1=wz[0][par][1], z2=wz[0][par][2], z3=wz[0][par][3];
      if (k1 > k0) { k0=k1; x0=x1; y0=y1; z0=z1; }
      if (k3 > k2) { k2=k3; x2=x3; y2=y3; z2=z3; }
      if (k2 > k0) { k0=k2; x0=x2; y0=y2; z0=z2; }
      lastA = (N_-1) - (int)(uint32_t)k0;
      lxA = x0; lyA = y0; lzA = z0;
    }
    {
      uint64_t k0 = wkey[1][par][0], k1 = wkey[1][par][1];
      uint64_t k2 = wkey[1][par][2], k3 = wkey[1][par][3];
      float x0=wx[1][par][0], x1=wx[1][par][1], x2=wx[1][par][2], x3=wx[1][par][3];
      float y0=wy[1][par][0], y1=wy[1][par][1], y2=wy[1][par][2], y3=wy[1][par][3];
      float z0=wz[1][par][0], z1=wz[1][par][1], z2=wz[1][par][2], z3=wz[1][par][3];
      if (k1 > k0) { k0=k1; x0=x1; y0=y1; z0=z1; }
      if (k3 > k2) { k2=k3; x2=x3; y2=y3; z2=z3; }
      if (k2 > k0) { k0=k2; x0=x2; y0=y2; z0=z2; }
      lastB = (N_-1) - (int)(uint32_t)k0;
      lxB = x0; lyB = y0; lzB = z0;
    }
  }
  __syncthreads();
  for (int s = t; s < S_; s += FT) {
    const int pa = hist[0][s];
    const int pb = hist[1][s];
    const size_t oA = ((size_t)bA*S_ + s)*3;
    const size_t oB = ((size_t)bB*S_ + s)*3;
    qpos_out[oA+0] = px[0][pa]; qpos_out[oA+1] = py[0][pa]; qpos_out[oA+2] = pz[0][pa];
    qpos_out[oB+0] = px[1][pb]; qpos_out[oB+1] = py[1][pb]; qpos_out[oB+2] = pz[1][pb];
  }
}

// ---------------- Kernel 2: radius ball query (one wave per query) ----------------
__global__ __launch_bounds__(256) void radius_kernel(
    const float* __restrict__ pos, const float* __restrict__ qpos,
    int* __restrict__ nbr, int* __restrict__ cnt_out)
{
  const int lane = threadIdx.x & 63;
  const int q = blockIdx.x * 4 + (threadIdx.x >> 6);
  const int b = q >> 10;                          // q / S_
  const float* pb = pos + (size_t)b * N_ * 3;
  const float qx = qpos[(size_t)q*3+0];
  const float qy = qpos[(size_t)q*3+1];
  const float qz = qpos[(size_t)q*3+2];
  int cnt = 0;
  for (int base = 0; base < N_; base += 64) {
    #pragma clang fp contract(off)
    const int i = base + lane;
    const float dx = qx - pb[i*3+0];
    const float dy = qy - pb[i*3+1];
    const float dz = qz - pb[i*3+2];
    const float d  = dx*dx + dy*dy + dz*dz;       // exact ref order, no FMA
    const bool valid = (d <= 0.04f);              // fl(0.04) == fl(python 0.2*0.2)
    const unsigned long long bal = __ballot(valid);
    const int below = __popcll(bal & ((1ull << lane) - 1ull));
    const int p = cnt + below;
    if (valid && p < K_) nbr[(size_t)q*K_ + p] = i;
    cnt += __popcll(bal);
    if (cnt >= K_) break;                         // first-K-by-index complete
  }
  const int c = (cnt < K_) ? cnt : K_;
  if (lane >= c && lane < K_) nbr[(size_t)q*K_ + lane] = 0;  // safe gather idx
  if (lane == 0) cnt_out[q] = c;
}

// ---------------- Kernel 3: xw = x @ W1[0:64,:]  (64 rows per block) ----------------
__global__ __launch_bounds__(256) void xw_kernel(
    const float* __restrict__ x, const float* __restrict__ W1,
    float* __restrict__ xw)
{
  __shared__ float xs[64*65];   // padded rows -> conflict-free column reads
  __shared__ float ws[64*64];
  const int t = threadIdx.x;
  const size_t rowbase = (size_t)blockIdx.x * 64;
  for (int k = t; k < 4096; k += 256) {
    xs[(k >> 6)*65 + (k & 63)] = x[rowbase*64 + k];
    ws[k] = W1[k];                                // rows 0..63 of W1[67][64]
  }
  __syncthreads();
  const int rg = t >> 4, cg = t & 15;
  const int r0 = rg*4, c0 = cg*4;
  float acc[4][4] = {};
  for (int i = 0; i < 64; ++i) {
    const float4 w = *(const float4*)&ws[i*64 + c0];
    #pragma unroll
    for (int j = 0; j < 4; ++j) {
      const float a = xs[(r0+j)*65 + i];
      acc[j][0] = fmaf(a, w.x, acc[j][0]);
      acc[j][1] = fmaf(a, w.y, acc[j][1]);
      acc[j][2] = fmaf(a, w.z, acc[j][2]);
      acc[j][3] = fmaf(a, w.w, acc[j][3]);
    }
  }
  #pragma unroll
  for (int j = 0; j < 4; ++j) {
    float4 v; v.x=acc[j][0]; v.y=acc[j][1]; v.z=acc[j][2]; v.w=acc[j][3];
    *(float4*)&xw[(rowbase + r0 + j)*64 + c0] = v;
  }
}

// ---------------- Kernel 4: gather + MLP + masked max (2 queries / block) ----------------
__global__ __launch_bounds__(256) void conv_kernel(
    const float* __restrict__ pos, const float* __restrict__ qpos,
    const int* __restrict__ nbr, const int* __restrict__ cnt,
    const float* __restrict__ xw,
    const float* __restrict__ W1, const float* __restrict__ b1,
    const float* __restrict__ W2, const float* __restrict__ b2,
    const float* __restrict__ W3, const float* __restrict__ b3,
    float* __restrict__ out)
{
  __shared__ float h1s[64*68];
  __shared__ float h2s[64*68];
  __shared__ float red[8*128];
  __shared__ int   nbrs[64];
  __shared__ float qps[8];
  __shared__ int   cnts[2];

  const int t  = threadIdx.x;
  const int q0 = blockIdx.x * 2;     // even -> both queries in same cloud
  const int b  = q0 >> 10;

  if (t < 64) nbrs[t] = nbr[(size_t)q0*K_ + t];
  if (t < 2)  cnts[t] = cnt[q0 + t];
  if (t < 6)  qps[(t/3)*4 + (t%3)] = qpos[(size_t)q0*3 + t];
  __syncthreads();

  // phase 1: h1[64 rows][64] = relu(xw[nbr] + rel @ W1[64:67] + b1)
  {
    const int c = t & 63;
    const int rsub = t >> 6;
    const float w1x = W1[64*64 + c];
    const float w1y = W1[65*64 + c];
    const float w1z = W1[66*64 + c];
    const float b1v = b1[c];
    #pragma unroll
    for (int it = 0; it < 16; ++it) {
      const int row = it*4 + rsub;
      const int lq  = row >> 5;
      const int j   = nbrs[row];
      const size_t gp = (size_t)b*N_ + j;
      const float xv = xw[gp*64 + c];
      const float rx = pos[gp*3+0] - qps[lq*4+0];
      const float ry = pos[gp*3+1] - qps[lq*4+1];
      const float rz = pos[gp*3+2] - qps[lq*4+2];
      float h = fmaf(rx, w1x, xv);
      h = fmaf(ry, w1y, h);
      h = fmaf(rz, w1z, h);
      h += b1v;
      h1s[row*68 + c] = fmaxf(h, 0.0f);
    }
  }
  __syncthreads();

  // phase 2: h2[64][64] = relu(h1 @ W2 + b2), 4x4 register tiles
  {
    const int rg = t >> 4, cg = t & 15;
    const int r0 = rg*4, c0 = cg*4;
    float acc[4][4] = {};
    for (int i = 0; i < 64; i += 4) {
      float a[4][4];
      #pragma unroll
      for (int j = 0; j < 4; ++j)
        *(float4*)&a[j][0] = *(const float4*)&h1s[(r0+j)*68 + i];
      #pragma unroll
      for (int di = 0; di < 4; ++di) {
        const float4 w = *(const float4*)&W2[(i+di)*64 + c0];
        #pragma unroll
        for (int j = 0; j < 4; ++j) {
          const float av = a[j][di];
          acc[j][0] = fmaf(av, w.x, acc[j][0]);
          acc[j][1] = fmaf(av, w.y, acc[j][1]);
          acc[j][2] = fmaf(av, w.z, acc[j][2]);
          acc[j][3] = fmaf(av, w.w, acc[j][3]);
        }
      }
    }
    const float4 bb = *(const float4*)&b2[c0];
    #pragma unroll
    for (int j = 0; j < 4; ++j) {
      float4 v;
      v.x = fmaxf(acc[j][0] + bb.x, 0.0f);
      v.y = fmaxf(acc[j][1] + bb.y, 0.0f);
      v.z = fmaxf(acc[j][2] + bb.z, 0.0f);
      v.w = fmaxf(acc[j][3] + bb.w, 0.0f);
      *(float4*)&h2s[(r0+j)*68 + c0] = v;
    }
  }
  __syncthreads();

  // phase 3: h3 = h2 @ W3 (+b3 after max); masked max over neighbors
  {
    const int rg = t >> 5, cg = t & 31;
    const int r0 = rg*8, c0 = cg*4;
    const int lq = rg >> 2;
    const int cq = cnts[lq];
    float acc[8][4] = {};
    for (int i = 0; i < 64; i += 4) {
      float a[8][4];
      #pragma unroll
      for (int j = 0; j < 8; ++j)
        *(float4*)&a[j][0] = *(const float4*)&h2s[(r0+j)*68 + i];
      #pragma unroll
      for (int di = 0; di < 4; ++di) {
        const float4 w = *(const float4*)&W3[(size_t)(i+di)*128 + c0];
        #pragma unroll
        for (int j = 0; j < 8; ++j) {
          const float av = a[j][di];
          acc[j][0] = fmaf(av, w.x, acc[j][0]);
          acc[j][1] = fmaf(av, w.y, acc[j][1]);
          acc[j][2] = fmaf(av, w.z, acc[j][2]);
          acc[j][3] = fmaf(av, w.w, acc[j][3]);
        }
      }
    }
    float pm0=-INFINITY, pm1=-INFINITY, pm2=-INFINITY, pm3=-INFINITY;
    #pragma unroll
    for (int j = 0; j < 8; ++j) {
      const int n = (r0 + j) & 31;
      if (n < cq) {
        pm0 = fmaxf(pm0, acc[j][0]);
        pm1 = fmaxf(pm1, acc[j][1]);
        pm2 = fmaxf(pm2, acc[j][2]);
        pm3 = fmaxf(pm3, acc[j][3]);
      }
    }
    float4 v; v.x=pm0; v.y=pm1; v.z=pm2; v.w=pm3;
    *(float4*)&red[rg*128 + c0] = v;
  }
  __syncthreads();
  {
    const int q = t >> 7, c = t & 127;
    const int cq = cnts[q];
    float v = -INFINITY;
    #pragma unroll
    for (int j = 0; j < 4; ++j) v = fmaxf(v, red[(q*4+j)*128 + c]);
    v = (cq > 0) ? (v + b3[c]) : 0.0f;   // b3 const per column: add after max
    v = fmaxf(v, 0.0f);
    out[(size_t)(q0 + q)*COUT_ + c] = v;
  }
}

extern "C" void kernel_launch(void* const* d_in, const int* in_sizes, int n_in,
                              void* d_out, int out_size, void* d_ws, size_t ws_size,
                              hipStream_t stream) {
  const float* x   = (const float*)d_in[0];
  const float* pos = (const float*)d_in[1];
  // d_in[2] = batch (unused: equal-size clouds)
  const float* W1  = (const float*)d_in[3];
  const float* b1  = (const float*)d_in[4];
  const float* W2  = (const float*)d_in[5];
  const float* b2  = (const float*)d_in[6];
  const float* W3  = (const float*)d_in[7];
  const float* b3  = (const float*)d_in[8];

  float* out    = (float*)d_out;                       // [NQ][128]
  float* qpos   = out + (size_t)NQ_*COUT_;             // [NQ][3]
  float* batchf = qpos + (size_t)NQ_*3;                // [NQ]

  char* ws = (char*)d_ws;
  float* xw = (float*)ws;                              // [B*N][64] = 16 MB
  int* nbr  = (int*)(ws + (size_t)B_*N_*64*sizeof(float));   // [NQ][K]
  int* cnt  = nbr + (size_t)NQ_*K_;                    // [NQ]

  hipLaunchKernelGGL(xw_kernel,     dim3((B_*N_)/64), dim3(256), 0, stream, x, W1, xw);
  hipLaunchKernelGGL(fps2_kernel,   dim3(B_/2),       dim3(FT),  0, stream, pos, qpos, batchf);
  hipLaunchKernelGGL(radius_kernel, dim3(NQ_/4),      dim3(256), 0, stream, pos, qpos, nbr, cnt);
  hipLaunchKernelGGL(conv_kernel,   dim3(NQ_/2),      dim3(256), 0, stream,
                     pos, qpos, nbr, cnt, xw, W1, b1, W2, b2, W3, b3, out);
}

// Round 6
// 917.330 us; speedup vs baseline: 1.8221x; 1.8221x over previous
//
#include <hip/hip_runtime.h>
#include <cstdint>
#include <cstddef>

#define B_    16
#define N_    4096
#define S_    1024
#define K_    32
#define COUT_ 128
#define NQ_   (B_*S_)

#define NBLK_     256     // exactly 1 block per CU (static LDS forces 1/CU)
#define NBLK_FPS  16
#define NXW_TILES 1024    // 64 rows each
#define NCONV_    8192    // 2 queries each, s-major across clouds

// flags layout (ints): [0]=ticket  [16+b]=progress  [32+b]=xwdone
//                      [64]=xw tile ctr  [80]=conv item ctr
#define F_TICKET 0
#define F_PROG   16
#define F_XWDONE 32
#define F_XWCTR  64
#define F_CVCTR  80

// ---- static shared union, padded to 90112 B -> exactly 1 block/CU ----
union __align__(16) SMem {
  struct {
    float px[N_], py[N_], pz[N_];          // 48 KiB
    int   hist[S_];                        // 4 KiB
    unsigned long long wkey[2][4];         // [parity][wave]
    float wx[2][4], wy[2][4], wz[2][4];    // winner coords per wave
  } fps;
  struct {
    float xs[64*65];                       // padded rows
    float ws[64*64];
  } xw;
  struct {
    float h1s[64*68];
    float h2s[64*68];
    float red[8*128];
    int   nbrs[64];
    float qps[8];
    int   cnts[2];
  } conv;
  char pad[90112];
};

// wave64 max-reduce of u64 key via DPP; lane 63 holds the result.
__device__ __forceinline__ uint64_t wave_max_u64_l63(uint64_t key) {
  uint32_t lo = (uint32_t)key, hi = (uint32_t)(key >> 32);
#define DPP_STEP(ctrl) { \
    uint32_t lo2 = (uint32_t)__builtin_amdgcn_update_dpp((int)lo, (int)lo, (ctrl), 0xf, 0xf, false); \
    uint32_t hi2 = (uint32_t)__builtin_amdgcn_update_dpp((int)hi, (int)hi, (ctrl), 0xf, 0xf, false); \
    const bool gt = (hi2 > hi) || (hi2 == hi && lo2 > lo); \
    hi = gt ? hi2 : hi; lo = gt ? lo2 : lo; \
  }
  DPP_STEP(0x111)  // row_shr:1
  DPP_STEP(0x112)  // row_shr:2
  DPP_STEP(0x114)  // row_shr:4
  DPP_STEP(0x118)  // row_shr:8
  DPP_STEP(0x142)  // row_bcast:15
  DPP_STEP(0x143)  // row_bcast:31
#undef DPP_STEP
  return ((uint64_t)hi << 32) | lo;
}

// -------------------- FPS producer role (R2's proven 677us body) --------------------
__device__ __forceinline__ void fps_role(
    SMem& sm, int b, const float* __restrict__ pos,
    float* __restrict__ qpos, float* __restrict__ batchf, volatile int* flags)
{
  const int t = threadIdx.x;
  const int lane = t & 63, wid = t >> 6;
  const float* pb = pos + (size_t)b * N_ * 3;

  for (int i = t; i < N_; i += 256) {
    sm.fps.px[i] = pb[i*3+0]; sm.fps.py[i] = pb[i*3+1]; sm.fps.pz[i] = pb[i*3+2];
  }
  for (int s = t; s < S_; s += 256) batchf[(size_t)b*S_ + s] = (float)b;
  __syncthreads();

  float rx[16], ry[16], rz[16], mind[16];
  #pragma unroll
  for (int k = 0; k < 16; ++k) {
    const int p = k*256 + t;
    rx[k] = sm.fps.px[p]; ry[k] = sm.fps.py[p]; rz[k] = sm.fps.pz[p];
    mind[k] = INFINITY;
  }

  int last = 0;
  float lx = sm.fps.px[0], ly = sm.fps.py[0], lz = sm.fps.pz[0];

  for (int s = 0; s < S_; ++s) {
    if (t == 0) sm.fps.hist[s] = last;
    if (s < S_-1) {
      float bm = -1.0f; int kb = 0;
      #pragma unroll
      for (int k = 0; k < 16; ++k) {
        #pragma clang fp contract(off)
        const float dx = rx[k]-lx;
        const float dy = ry[k]-ly;
        const float dz = rz[k]-lz;
        const float d  = dx*dx + dy*dy + dz*dz;   // exact ref order, no FMA
        const float m  = fminf(mind[k], d);
        mind[k] = m;
        if (m > bm) { bm = m; kb = k; }           // strict > keeps lowest k
      }
      // max key == (max dist, then min point index): lo = 4095 - p
      uint64_t key = ((uint64_t)__float_as_uint(bm) << 32)
                   | (uint32_t)((N_-1) - (kb*256 + t));
      key = wave_max_u64_l63(key);
      const int par = s & 1;
      if (lane == 63) {
        const int p = (N_-1) - (int)(uint32_t)key;
        sm.fps.wkey[par][wid] = key;              // prefetch winner coords pre-barrier
        sm.fps.wx[par][wid] = sm.fps.px[p];
        sm.fps.wy[par][wid] = sm.fps.py[p];
        sm.fps.wz[par][wid] = sm.fps.pz[p];
      }
      __syncthreads();                            // single barrier per step
      {
        uint64_t k0 = sm.fps.wkey[par][0], k1 = sm.fps.wkey[par][1];
        uint64_t k2 = sm.fps.wkey[par][2], k3 = sm.fps.wkey[par][3];
        float x0=sm.fps.wx[par][0], x1=sm.fps.wx[par][1], x2=sm.fps.wx[par][2], x3=sm.fps.wx[par][3];
        float y0=sm.fps.wy[par][0], y1=sm.fps.wy[par][1], y2=sm.fps.wy[par][2], y3=sm.fps.wy[par][3];
        float z0=sm.fps.wz[par][0], z1=sm.fps.wz[par][1], z2=sm.fps.wz[par][2], z3=sm.fps.wz[par][3];
        if (k1 > k0) { k0=k1; x0=x1; y0=y1; z0=z1; }
        if (k3 > k2) { k2=k3; x2=x3; y2=y3; z2=z3; }
        if (k2 > k0) { k0=k2; x0=x2; y0=y2; z0=z2; }
        last = (N_-1) - (int)(uint32_t)k0;
        lx = x0; ly = y0; lz = z0;
      }
    }
    if ((s & 31) == 31) {                         // progressive publish
      if (t < 32) {
        const int row = s - 31 + t;
        const int p = sm.fps.hist[row];
        const size_t o = ((size_t)b*S_ + row)*3;
        qpos[o+0] = sm.fps.px[p];
        qpos[o+1] = sm.fps.py[p];
        qpos[o+2] = sm.fps.pz[p];
      }
      if (t == 0)
        __hip_atomic_store((int*)&flags[F_PROG + b], s+1, __ATOMIC_RELEASE, __HIP_MEMORY_SCOPE_AGENT);
    }
  }
}

// -------------------- one xw tile: xw[tile*64 .. +64) = x @ W1[0:64] --------------------
__device__ __forceinline__ void xw_tile_body(
    SMem& sm, int tile, const float* __restrict__ x,
    const float* __restrict__ W1, float* __restrict__ xw)
{
  const int t = threadIdx.x;
  const size_t rowbase = (size_t)tile * 64;
  for (int k = t; k < 4096; k += 256) {
    sm.xw.xs[(k >> 6)*65 + (k & 63)] = x[rowbase*64 + k];
    sm.xw.ws[k] = W1[k];                          // rows 0..63 of W1[67][64]
  }
  __syncthreads();
  const int rg = t >> 4, cg = t & 15;
  const int r0 = rg*4, c0 = cg*4;
  float acc[4][4] = {};
  for (int i = 0; i < 64; ++i) {
    const float4 w = *(const float4*)&sm.xw.ws[i*64 + c0];
    #pragma unroll
    for (int j = 0; j < 4; ++j) {
      const float a = sm.xw.xs[(r0+j)*65 + i];
      acc[j][0] = fmaf(a, w.x, acc[j][0]);
      acc[j][1] = fmaf(a, w.y, acc[j][1]);
      acc[j][2] = fmaf(a, w.z, acc[j][2]);
      acc[j][3] = fmaf(a, w.w, acc[j][3]);
    }
  }
  #pragma unroll
  for (int j = 0; j < 4; ++j) {
    float4 v; v.x=acc[j][0]; v.y=acc[j][1]; v.z=acc[j][2]; v.w=acc[j][3];
    *(float4*)&xw[(rowbase + r0 + j)*64 + c0] = v;
  }
}

// -------------------- one conv item: inline radius + MLP + masked max --------------------
__device__ __forceinline__ void conv_item_body(
    SMem& sm, int bb, int q0, const float* __restrict__ pos, const float* __restrict__ qpos,
    const float* __restrict__ xw,
    const float* __restrict__ W1, const float* __restrict__ b1,
    const float* __restrict__ W2, const float* __restrict__ b2,
    const float* __restrict__ W3, const float* __restrict__ b3,
    float* __restrict__ out)
{
  const int t = threadIdx.x;
  const int wid = t >> 6, lane = t & 63;

  // inline radius: waves 0,1 scan for q0, q0+1
  if (wid < 2) {
    const int q = q0 + wid;
    const float* pb = pos + (size_t)bb * N_ * 3;
    const float qx = qpos[(size_t)q*3+0];
    const float qy = qpos[(size_t)q*3+1];
    const float qz = qpos[(size_t)q*3+2];
    int cnt = 0;
    for (int base = 0; base < N_; base += 64) {
      #pragma clang fp contract(off)
      const int i = base + lane;
      const float dx = qx - pb[i*3+0];
      const float dy = qy - pb[i*3+1];
      const float dz = qz - pb[i*3+2];
      const float d  = dx*dx + dy*dy + dz*dz;     // exact ref order, no FMA
      const bool valid = (d <= 0.04f);            // fl(0.04) == fl(python 0.2*0.2)
      const unsigned long long bal = __ballot(valid);
      const int below = __popcll(bal & ((1ull << lane) - 1ull));
      const int p = cnt + below;
      if (valid && p < K_) sm.conv.nbrs[wid*K_ + p] = i;
      cnt += __popcll(bal);
      if (cnt >= K_) break;                       // first-K-by-index complete
    }
    const int c = (cnt < K_) ? cnt : K_;
    if (lane >= c && lane < K_) sm.conv.nbrs[wid*K_ + lane] = 0;
    if (lane == 0) sm.conv.cnts[wid] = c;
  }
  if (t < 6) sm.conv.qps[(t/3)*4 + (t%3)] = qpos[(size_t)q0*3 + t];
  __syncthreads();

  // phase 1: h1[64][64] = relu(xw[nbr] + rel @ W1[64:67] + b1)
  {
    const int c = t & 63;
    const int rsub = t >> 6;
    const float w1x = W1[64*64 + c];
    const float w1y = W1[65*64 + c];
    const float w1z = W1[66*64 + c];
    const float b1v = b1[c];
    #pragma unroll
    for (int it = 0; it < 16; ++it) {
      const int row = it*4 + rsub;
      const int lq  = row >> 5;
      const int jn  = sm.conv.nbrs[row];
      const size_t gp = (size_t)bb*N_ + jn;
      const float xv = xw[gp*64 + c];
      const float rxx = pos[gp*3+0] - sm.conv.qps[lq*4+0];
      const float ryy = pos[gp*3+1] - sm.conv.qps[lq*4+1];
      const float rzz = pos[gp*3+2] - sm.conv.qps[lq*4+2];
      float h = fmaf(rxx, w1x, xv);
      h = fmaf(ryy, w1y, h);
      h = fmaf(rzz, w1z, h);
      h += b1v;
      sm.conv.h1s[row*68 + c] = fmaxf(h, 0.0f);
    }
  }
  __syncthreads();

  // phase 2: h2 = relu(h1 @ W2 + b2)
  {
    const int rg = t >> 4, cg = t & 15;
    const int r0 = rg*4, c0 = cg*4;
    float acc[4][4] = {};
    for (int i = 0; i < 64; i += 4) {
      float a[4][4];
      #pragma unroll
      for (int jj = 0; jj < 4; ++jj)
        *(float4*)&a[jj][0] = *(const float4*)&sm.conv.h1s[(r0+jj)*68 + i];
      #pragma unroll
      for (int di = 0; di < 4; ++di) {
        const float4 w = *(const float4*)&W2[(i+di)*64 + c0];
        #pragma unroll
        for (int jj = 0; jj < 4; ++jj) {
          const float av = a[jj][di];
          acc[jj][0] = fmaf(av, w.x, acc[jj][0]);
          acc[jj][1] = fmaf(av, w.y, acc[jj][1]);
          acc[jj][2] = fmaf(av, w.z, acc[jj][2]);
          acc[jj][3] = fmaf(av, w.w, acc[jj][3]);
        }
      }
    }
    const float4 bbv = *(const float4*)&b2[c0];
    #pragma unroll
    for (int jj = 0; jj < 4; ++jj) {
      float4 v;
      v.x = fmaxf(acc[jj][0] + bbv.x, 0.0f);
      v.y = fmaxf(acc[jj][1] + bbv.y, 0.0f);
      v.z = fmaxf(acc[jj][2] + bbv.z, 0.0f);
      v.w = fmaxf(acc[jj][3] + bbv.w, 0.0f);
      *(float4*)&sm.conv.h2s[(r0+jj)*68 + c0] = v;
    }
  }
  __syncthreads();

  // phase 3: h3 = h2 @ W3; masked max (+b3 after max)
  {
    const int rg = t >> 5, cg = t & 31;
    const int r0 = rg*8, c0 = cg*4;
    const int lq = rg >> 2;
    const int cq = sm.conv.cnts[lq];
    float acc[8][4] = {};
    for (int i = 0; i < 64; i += 4) {
      float a[8][4];
      #pragma unroll
      for (int jj = 0; jj < 8; ++jj)
        *(float4*)&a[jj][0] = *(const float4*)&sm.conv.h2s[(r0+jj)*68 + i];
      #pragma unroll
      for (int di = 0; di < 4; ++di) {
        const float4 w = *(const float4*)&W3[(size_t)(i+di)*128 + c0];
        #pragma unroll
        for (int jj = 0; jj < 8; ++jj) {
          const float av = a[jj][di];
          acc[jj][0] = fmaf(av, w.x, acc[jj][0]);
          acc[jj][1] = fmaf(av, w.y, acc[jj][1]);
          acc[jj][2] = fmaf(av, w.z, acc[jj][2]);
          acc[jj][3] = fmaf(av, w.w, acc[jj][3]);
        }
      }
    }
    float pm0=-INFINITY, pm1=-INFINITY, pm2=-INFINITY, pm3=-INFINITY;
    #pragma unroll
    for (int jj = 0; jj < 8; ++jj) {
      const int n = (r0 + jj) & 31;
      if (n < cq) {
        pm0 = fmaxf(pm0, acc[jj][0]);
        pm1 = fmaxf(pm1, acc[jj][1]);
        pm2 = fmaxf(pm2, acc[jj][2]);
        pm3 = fmaxf(pm3, acc[jj][3]);
      }
    }
    float4 v; v.x=pm0; v.y=pm1; v.z=pm2; v.w=pm3;
    *(float4*)&sm.conv.red[rg*128 + c0] = v;
  }
  __syncthreads();
  {
    const int q = t >> 7, c = t & 127;
    const int cq = sm.conv.cnts[q];
    float v = -INFINITY;
    #pragma unroll
    for (int jj = 0; jj < 4; ++jj) v = fmaxf(v, sm.conv.red[(q*4+jj)*128 + c]);
    v = (cq > 0) ? (v + b3[c]) : 0.0f;   // b3 const per column: add after max
    v = fmaxf(v, 0.0f);
    out[(size_t)(q0 + q)*COUT_ + c] = v;
  }
}

// -------------------- persistent worker role --------------------
__device__ __forceinline__ void worker_role(
    SMem& sm, int& slot_s,
    const float* __restrict__ x, const float* __restrict__ pos,
    const float* __restrict__ qpos, float* __restrict__ xw,
    const float* __restrict__ W1, const float* __restrict__ b1,
    const float* __restrict__ W2, const float* __restrict__ b2,
    const float* __restrict__ W3, const float* __restrict__ b3,
    float* __restrict__ out, int* flags)
{
  const int t = threadIdx.x;

  // ---- drain xw tiles ----
  for (;;) {
    __syncthreads();
    if (t == 0) slot_s = atomicAdd(&flags[F_XWCTR], 1);
    __syncthreads();
    const int tile = slot_s;
    if (tile >= NXW_TILES) break;
    xw_tile_body(sm, tile, x, W1, xw);
    __syncthreads();               // block-wide stores drained before flag
    if (t == 0)
      __hip_atomic_fetch_add(&flags[F_XWDONE + (tile >> 6)], 1, __ATOMIC_RELEASE, __HIP_MEMORY_SCOPE_AGENT);
  }

  // ---- drain conv items (s-major across clouds, paced by fps frontier) ----
  for (;;) {
    __syncthreads();
    if (t == 0) {
      const int it = atomicAdd(&flags[F_CVCTR], 1);
      slot_s = it;
      if (it < NCONV_) {
        const int bb = it & 15, pair = it >> 4;
        while (__hip_atomic_load(&flags[F_XWDONE + bb], __ATOMIC_ACQUIRE, __HIP_MEMORY_SCOPE_AGENT) < 64)
          __builtin_amdgcn_s_sleep(32);
        const int need = pair*2 + 2;
        while (__hip_atomic_load(&flags[F_PROG + bb], __ATOMIC_ACQUIRE, __HIP_MEMORY_SCOPE_AGENT) < need)
          __builtin_amdgcn_s_sleep(32);
      }
    }
    __syncthreads();
    const int item = slot_s;
    if (item >= NCONV_) break;
    const int bb = item & 15, pair = item >> 4;
    conv_item_body(sm, bb, bb*S_ + pair*2, pos, qpos, xw,
                   W1, b1, W2, b2, W3, b3, out);
  }
}

// -------------------- mega kernel: 256 blocks, 1 per CU --------------------
__global__ __launch_bounds__(256) void mega_kernel(
    const float* __restrict__ x, const float* __restrict__ pos,
    const float* __restrict__ W1, const float* __restrict__ b1,
    const float* __restrict__ W2, const float* __restrict__ b2,
    const float* __restrict__ W3, const float* __restrict__ b3,
    float* __restrict__ out, float* __restrict__ qpos, float* __restrict__ batchf,
    float* __restrict__ xw, int* flags)
{
  __shared__ SMem sm;              // 90112 B static -> exactly 1 block/CU
  __shared__ int tk_s;
  __shared__ int slot_s;
  if (threadIdx.x == 0) tk_s = atomicAdd(&flags[F_TICKET], 1);  // arrival order
  __syncthreads();
  const int tk = tk_s;

  if (tk < NBLK_FPS) {
    fps_role(sm, tk, pos, qpos, batchf, flags);
  } else {
    worker_role(sm, slot_s, x, pos, qpos, xw, W1, b1, W2, b2, W3, b3, out, flags);
  }
}

extern "C" void kernel_launch(void* const* d_in, const int* in_sizes, int n_in,
                              void* d_out, int out_size, void* d_ws, size_t ws_size,
                              hipStream_t stream) {
  const float* x   = (const float*)d_in[0];
  const float* pos = (const float*)d_in[1];
  // d_in[2] = batch (unused: equal-size clouds)
  const float* W1  = (const float*)d_in[3];
  const float* b1  = (const float*)d_in[4];
  const float* W2  = (const float*)d_in[5];
  const float* b2  = (const float*)d_in[6];
  const float* W3  = (const float*)d_in[7];
  const float* b3  = (const float*)d_in[8];

  float* out    = (float*)d_out;                       // [NQ][128]
  float* qpos   = out + (size_t)NQ_*COUT_;             // [NQ][3]
  float* batchf = qpos + (size_t)NQ_*3;                // [NQ]

  char* ws = (char*)d_ws;
  float* xw  = (float*)ws;                             // [B*N][64] = 16 MB
  int* flags = (int*)(ws + (size_t)B_*N_*64*sizeof(float));

  hipMemsetAsync(flags, 0, 512, stream);               // re-zero flags every call
  hipLaunchKernelGGL(mega_kernel, dim3(NBLK_), dim3(256), 0, stream,
                     x, pos, W1, b1, W2, b2, W3, b3, out, qpos, batchf, xw, flags);
}